// Round 14
// baseline (283.111 us; speedup 1.0000x reference)
//
#include <hip/hip_runtime.h>
#include <math.h>

// Problem constants
#define NS     16
#define T_LEN  8192
#define BATCH  8
#define CH     32

// Tiling
#define TW     248        // outputs per block (62 per wave + 2-col shfl halo)
#define BT     256
#define NTILES 34         // ceil(8192/248)
#define RS     260        // cwt row stride (dwords)
#define NKC    33         // K chunks of 16: shared tap window k' in [0,528)
#define XWELEM 784        // x window elems per copy
#define XCS    800        // copy stride in f16 (400 dwords ≡ 16 mod 32)
#define NCPY   2          // shifted copies (b32 path: frag base ≡ 0 mod 2 f16)
#define NFRAG  (NKC*512)  // wavelet fragment f16 count per stream

typedef _Float16 f16x2 __attribute__((ext_vector_type(2)));
typedef _Float16 f16x8 __attribute__((ext_vector_type(8)));
typedef float    f32x16 __attribute__((ext_vector_type(16)));

// Per-scale constants (validated rounds 1-13)
constexpr int LT[NS]   = {13,17,23,31,41,55,75,103,139,191,259,351,477,513,513,513};
constexpr int PADT[NS] = {6,8,11,15,20,27,37,51,69,95,129,175,238,256,256,256};

__device__ __forceinline__ float gelu_exact(float v) {
    return 0.5f * v * (1.0f + erff(v * 0.70710678118654752440f));
}

// Regenerate wavelet B-fragment streams (hi + lo split-f16) every launch.
// Element (kc, lane, j) at [kc*512 + lane*8 + j] holds B[k=8*(lane>>5)+j][n=lane&31]
// for chunk kc: tap of scale s=n>>1 (n even=real, odd=imag) at
// j_tap = (kc*16 + k) - 256 + pad_s.  w_f32 = hi + lo with hi=(f16)w_f32.
__global__ void wavelet_init(_Float16* __restrict__ whi, _Float16* __restrict__ wlo) {
    int idx0   = blockIdx.x * blockDim.x + threadIdx.x;
    int stride = gridDim.x * blockDim.x;
    for (int idx = idx0; idx < NFRAG; idx += stride) {
        int kc   = idx >> 9;
        int r    = idx & 511;
        int lane = r >> 3;
        int j    = r & 7;
        int n    = lane & 31;
        int h    = lane >> 5;
        int kp   = kc * 16 + 8 * h + j;      // k' in [0,528+15]
        int s    = n >> 1;
        int ri   = n & 1;
        int L    = LT[s];
        int jt   = kp - 256 + PADT[s];
        float wf = 0.f;
        if (jt >= 0 && jt < L) {
            double e  = (s == NS - 1) ? log10(200.0)
                                      : (log10(2.0) + (double)s * ((log10(200.0) - log10(2.0)) / 15.0));
            double sc = pow(10.0, e);
            double lo = -(double)((L + 1) / 2);   // Python (-L)//2, L odd
            double hi =  (double)(L / 2);
            double st = (hi - lo) / (double)(L - 1);
            double t  = (jt == L - 1) ? hi : (lo + (double)jt * st);
            double ts = t / sc;
            double nm = 1.0 / (pow(M_PI, 0.25) * sqrt(sc));
            double g  = nm * exp(-(ts * ts) * 0.5);
            wf = (float)(ri ? (g * sin(5.0 * ts)) : (g * cos(5.0 * ts)));
        }
        _Float16 hv = (_Float16)wf;
        whi[idx] = hv;
        wlo[idx] = (_Float16)(wf - (float)hv);
    }
}

__global__ __launch_bounds__(BT, 6) void wlsc_main(
    const float* __restrict__ x,
    const float* __restrict__ w1, const float* __restrict__ b1,
    const float* __restrict__ w2, const float* __restrict__ b2,
    const float* __restrict__ blend_logit,
    const float* __restrict__ lsc,
    const _Float16* __restrict__ wfh,
    const _Float16* __restrict__ wfl,
    float* __restrict__ out)
{
    __shared__ float cwtb[NS * RS];                          // 16640 B
    __shared__ __align__(16) char ubuf[2 * NCPY * XCS * 2];  // 6400 B: split-f16 x copies
    __shared__ float corr[NS];
    _Float16* xch = (_Float16*)ubuf;          // [NCPY][XCS] hi copies
    _Float16* xcl = xch + NCPY * XCS;         // [NCPY][XCS] lo copies
    // total LDS = 16640 + 6400 + 64 = 23104 B -> 6 blocks/CU

    const int tid  = threadIdx.x;
    const int tile = blockIdx.x;
    const int bc   = blockIdx.y;
    const int t0   = tile * TW;
    const int c    = bc & (CH - 1);
    const float* xbc = x + (size_t)bc * T_LEN;

    if (tid < NS) corr[tid] = expf(lsc[tid]);

    // ---- stage x window as split-f16 into 2 shifted copies:
    // xc[cp][u] = x[t0-258+u+cp]; one global load per element v, guarded stores ----
    for (int v = tid; v < XWELEM + NCPY; v += BT) {
        int g = t0 - 258 + v;
        if (g < 0)      g = -g;
        if (g >= T_LEN) g = 2 * T_LEN - 2 - g;
        float xv = xbc[g];
        _Float16 hv = (_Float16)xv;
        _Float16 lv = (_Float16)(xv - (float)hv);
        #pragma unroll
        for (int cp = 0; cp < NCPY; ++cp) {
            int idx = v - cp;
            if ((unsigned)idx < XWELEM) {
                xch[cp * XCS + idx] = hv;
                xcl[cp * XCS + idx] = lv;
            }
        }
    }
    __syncthreads();

    // ---- stage 1: CWT via mfma_f32_32x32x16_f16, split-f16 3-product scheme:
    // D = Ah*Bh + Ah*Bl + Al*Bh.  Hankel reuse: frag(mt0+1, kc) = frag(mt0, kc+2),
    // 3-deep rotating register queue loads each fragment once.
    // A-frags read as 4x ds_read_b32 (copy cp = m&1 gives 4B alignment;
    // 1 lane/bank per half-wave — no structural wide-access serialization). ----
    const int lane = tid & 63;
    const int wid  = tid >> 6;
    const int m    = lane & 31;
    const int h    = lane >> 5;
    const int mt0  = 2 * wid;
    f32x16 acc0, acc1;
    #pragma unroll
    for (int i = 0; i < 16; ++i) { acc0[i] = 0.f; acc1[i] = 0.f; }

    const int abase = (m & 1) * XCS + ((m & ~1) + 8 * h) + mt0 * 32;
    const _Float16* pah = xch + abase;
    const _Float16* pal = xcl + abase;
    const f16x8* wh = reinterpret_cast<const f16x8*>(wfh);
    const f16x8* wl = reinterpret_cast<const f16x8*>(wfl);

    // F(j) = A-frag for x range starting at mt0*32 + 16j (four b32, 4B-aligned)
#define LOADF(p, j) ({                                                        \
        f16x2 _a = *(const f16x2*)((p) + (j) * 16);                           \
        f16x2 _b = *(const f16x2*)((p) + (j) * 16 + 2);                       \
        f16x2 _c = *(const f16x2*)((p) + (j) * 16 + 4);                       \
        f16x2 _d = *(const f16x2*)((p) + (j) * 16 + 6);                       \
        f16x2 _e2 = __builtin_shufflevector(_a, _b, 0, 1);                    \
        (void)_e2;                                                            \
        f16x8 _r;                                                             \
        _r[0]=_a[0]; _r[1]=_a[1]; _r[2]=_b[0]; _r[3]=_b[1];                   \
        _r[4]=_c[0]; _r[5]=_c[1]; _r[6]=_d[0]; _r[7]=_d[1];                   \
        _r; })

    f16x8 Fh0 = LOADF(pah, 0), Fl0 = LOADF(pal, 0);
    f16x8 Fh1 = LOADF(pah, 1), Fl1 = LOADF(pal, 1);
    #pragma unroll 3
    for (int kc = 0; kc < NKC; ++kc) {
        f16x8 Fh2 = LOADF(pah, kc + 2);        // fresh: serves mt1 now, mt0 at kc+2
        f16x8 Fl2 = LOADF(pal, kc + 2);
        f16x8 bh = wh[kc * 64 + lane];         // global, L1/L2-hit
        f16x8 bl = wl[kc * 64 + lane];
        // mt0 products use queue head (loaded 2 iterations ago — no load stall)
        acc0 = __builtin_amdgcn_mfma_f32_32x32x16_f16(Fh0, bh, acc0, 0, 0, 0);
        acc0 = __builtin_amdgcn_mfma_f32_32x32x16_f16(Fh0, bl, acc0, 0, 0, 0);
        acc0 = __builtin_amdgcn_mfma_f32_32x32x16_f16(Fl0, bh, acc0, 0, 0, 0);
        // mt1 = mt0+1 products use the fresh fragment (= frag(mt0, kc+2))
        acc1 = __builtin_amdgcn_mfma_f32_32x32x16_f16(Fh2, bh, acc1, 0, 0, 0);
        acc1 = __builtin_amdgcn_mfma_f32_32x32x16_f16(Fh2, bl, acc1, 0, 0, 0);
        acc1 = __builtin_amdgcn_mfma_f32_32x32x16_f16(Fl2, bh, acc1, 0, 0, 0);
        Fh0 = Fh1; Fl0 = Fl1;
        Fh1 = Fh2; Fl1 = Fl2;
    }
#undef LOADF

    // magnitudes: pair (r,i) across lanes n, n^1; even-n lanes store to cwtb.
    // C/D layout: col=lane&31, row=(reg&3)+8*(reg>>2)+4*(lane>>5)  [m74/m101]
    const int s_mine = (lane & 31) >> 1;
    #pragma unroll
    for (int half = 0; half < 2; ++half) {
        f32x16& acc = half ? acc1 : acc0;
        const int mt = mt0 + half;
        #pragma unroll
        for (int g = 0; g < 4; ++g) {
            float4 mag;
            #pragma unroll
            for (int e = 0; e < 4; ++e) {
                float cr = acc[4 * g + e];
                float ci = __shfl_xor(cr, 1);
                float mg = sqrtf(cr * cr + ci * ci);
                int tt = mt * 32 + 8 * g + 4 * h + e;
                int ta = t0 - 2 + tt;                 // zero outside [0,T)
                if ((unsigned)ta >= T_LEN) mg = 0.f;
                (&mag.x)[e] = mg;
            }
            if ((lane & 1) == 0)
                *reinterpret_cast<float4*>(cwtb + s_mine * RS + mt * 32 + 8 * g + 4 * h) = mag;
        }
    }
    __syncthreads();

    // per-channel weights -> registers
    float W1r[9], W2r[9];
    #pragma unroll
    for (int k = 0; k < 9; ++k) { W1r[k] = w1[c * 9 + k]; W2r[k] = w2[c * 9 + k]; }
    const float B1v = b1[c], B2v = b2[c];
    const float blend = 1.f / (1.f + expf(-blend_logit[0]));

    // ---- stages 2+3 fused: h1 kept in registers, neighbor columns via shfl.
    // Wave wid owns h1 columns tt1 = 62*wid + lane (lanes 62,63 = halo),
    // outputs tt2 = 62*wid + lane for lane < 62. ----
    {
        const int tt1 = 62 * wid + lane;
        const int ta  = t0 - 1 + tt1;
        const bool inb = (unsigned)ta < T_LEN;
        float h1r[NS];     // h1[s] for this column
        float rawcv[NS];   // raw cwt[s][tt1+2] (= cv for stage 3)

        // stage 2: sliding rows, 3 b32 LDS reads per row
        {
            float p0 = 0.f, p1 = 0.f, p2 = 0.f;
            float c0, c1, c2;
            {
                const float* r = cwtb + tt1;
                float cr = corr[0];
                float r2 = r[2];
                rawcv[0] = r2;
                c0 = r[0] * cr; c1 = r[1] * cr; c2 = r2 * cr;
            }
            #pragma unroll
            for (int s = 0; s < NS; ++s) {
                float n0 = 0.f, n1 = 0.f, n2 = 0.f;
                if (s + 1 < NS) {
                    const float* r = cwtb + (s + 1) * RS + tt1;
                    float cr = corr[s + 1];
                    float r2 = r[2];
                    rawcv[s + 1] = r2;
                    n0 = r[0] * cr; n1 = r[1] * cr; n2 = r2 * cr;
                }
                float acc = B1v;
                acc = fmaf(p0, W1r[0], acc); acc = fmaf(p1, W1r[1], acc); acc = fmaf(p2, W1r[2], acc);
                acc = fmaf(c0, W1r[3], acc); acc = fmaf(c1, W1r[4], acc); acc = fmaf(c2, W1r[5], acc);
                acc = fmaf(n0, W1r[6], acc); acc = fmaf(n1, W1r[7], acc); acc = fmaf(n2, W1r[8], acc);
                h1r[s] = inb ? gelu_exact(acc) : 0.f;
                p0 = c0; p1 = c1; p2 = c2;
                c0 = n0; c1 = n1; c2 = n2;
            }
        }

        // stage 3: columns tt2+{0,1,2} = lanes lane, lane+1, lane+2 via shfl_down
        const int tt2 = tt1;
        const int t   = t0 + tt2;
        float racc = 0.f;
        float pa = 0.f, pb = 0.f, pc = 0.f;
        float ca, cb, cc;
        {
            ca = h1r[0];
            cb = __shfl_down(ca, 1);
            cc = __shfl_down(ca, 2);
        }
        #pragma unroll
        for (int s = 0; s < NS; ++s) {
            float na = 0.f, nb = 0.f, nc = 0.f;
            if (s + 1 < NS) {
                na = h1r[s + 1];
                nb = __shfl_down(na, 1);
                nc = __shfl_down(na, 2);
            }
            float acc = B2v;
            acc = fmaf(pa, W2r[0], acc); acc = fmaf(pb, W2r[1], acc); acc = fmaf(pc, W2r[2], acc);
            acc = fmaf(ca, W2r[3], acc); acc = fmaf(cb, W2r[4], acc); acc = fmaf(cc, W2r[5], acc);
            acc = fmaf(na, W2r[6], acc); acc = fmaf(nb, W2r[7], acc); acc = fmaf(nc, W2r[8], acc);
            float h2v = gelu_exact(acc);
            float cv  = rawcv[s];
            float num = blend * h2v + (1.f - blend) * cv;
            racc += num / (cv + 1e-8f);
            pa = ca; pb = cb; pc = cc;
            ca = na; cb = nb; cc = nc;
        }
        if (lane < 62 && t < T_LEN)
            out[(size_t)bc * T_LEN + t] = xbc[t] * racc * (1.f / 16.f);
    }
}

extern "C" void kernel_launch(void* const* d_in, const int* in_sizes, int n_in,
                              void* d_out, int out_size, void* d_ws, size_t ws_size,
                              hipStream_t stream) {
    const float* x  = (const float*)d_in[0];
    const float* w1 = (const float*)d_in[1];
    const float* b1 = (const float*)d_in[2];
    const float* w2 = (const float*)d_in[3];
    const float* b2 = (const float*)d_in[4];
    const float* bl = (const float*)d_in[5];
    const float* ls = (const float*)d_in[6];
    float* out = (float*)d_out;

    _Float16* whi = (_Float16*)d_ws;          // NFRAG f16
    _Float16* wlo = whi + NFRAG;              // NFRAG f16

    hipLaunchKernelGGL(wavelet_init, dim3(68), dim3(256), 0, stream, whi, wlo);

    dim3 grid(NTILES, BATCH * CH);
    hipLaunchKernelGGL(wlsc_main, grid, dim3(BT), 0, stream,
                       x, w1, b1, w2, b2, bl, ls, whi, wlo, out);
}

// Round 15
// 226.119 us; speedup vs baseline: 1.2520x; 1.2520x over previous
//
#include <hip/hip_runtime.h>
#include <math.h>

// Problem constants
#define NS     16
#define T_LEN  8192
#define BATCH  8
#define CH     32

// Tiling
#define TW     248        // outputs per block (62 per wave + 2-col shfl halo)
#define BT     256
#define NTILES 34         // ceil(8192/248)
#define RS     260        // cwt row stride (dwords)
#define XWELEM 800        // x window elems per copy (u = tt + k', k' < 544)
#define XCS    800        // copy stride in f16
#define NCPY   2          // shifted copies (b32 path: frag base ≡ 0 mod 2 f16)
// Two scale groups, 16x16x32 MFMA (N=16 cols = 8 scales x r/i):
//   group 1: scales 8-15, k' in [0,544), 17 K-chunks of 32
//   group 0: scales 0-7,  k' in [192,320), 4 K-chunks (taps lie in [205,308))
#define NQ0    4
#define NQ1    17
#define KOFF0  192
#define NCHUNK (NQ0 + NQ1)
#define NFRAG  (NCHUNK * 512)   // f16 per stream (10752)

typedef _Float16 f16x2 __attribute__((ext_vector_type(2)));
typedef _Float16 f16x8 __attribute__((ext_vector_type(8)));
typedef float    f32x4 __attribute__((ext_vector_type(4)));

// Per-scale constants (validated rounds 1-14)
constexpr int LT[NS]   = {13,17,23,31,41,55,75,103,139,191,259,351,477,513,513,513};
constexpr int PADT[NS] = {6,8,11,15,20,27,37,51,69,95,129,175,238,256,256,256};

__device__ __forceinline__ float gelu_exact(float v) {
    return 0.5f * v * (1.0f + erff(v * 0.70710678118654752440f));
}

// Wavelet B-fragment streams (hi+lo split-f16) for 16x16x32 MFMA.
// Chunk ci (<NQ0: group0 q=ci; else group1 q=ci-NQ0). Element (ci, lane, j) at
// [ci*512 + lane*8 + j] holds B[k=8*(lane>>4)+j][n=lane&15]: tap of scale
// s = 8*grp + (n>>1) (n even=real, odd=imag) at j_tap = koff+32q+k - 256 + pad_s.
__global__ void wavelet_init(_Float16* __restrict__ whi, _Float16* __restrict__ wlo) {
    int idx0   = blockIdx.x * blockDim.x + threadIdx.x;
    int stride = gridDim.x * blockDim.x;
    for (int idx = idx0; idx < NFRAG; idx += stride) {
        int ci   = idx >> 9;
        int r    = idx & 511;
        int l    = r >> 3;
        int j    = r & 7;
        int grp  = (ci >= NQ0) ? 1 : 0;
        int q    = grp ? (ci - NQ0) : ci;
        int koff = grp ? 0 : KOFF0;
        int n    = l & 15;
        int hq   = l >> 4;
        int kp   = koff + 32 * q + 8 * hq + j;
        int s    = 8 * grp + (n >> 1);
        int ri   = n & 1;
        int L    = LT[s];
        int jt   = kp - 256 + PADT[s];
        float wf = 0.f;
        if (jt >= 0 && jt < L) {
            double e  = (s == NS - 1) ? log10(200.0)
                                      : (log10(2.0) + (double)s * ((log10(200.0) - log10(2.0)) / 15.0));
            double sc = pow(10.0, e);
            double lo = -(double)((L + 1) / 2);   // Python (-L)//2, L odd
            double hi =  (double)(L / 2);
            double st = (hi - lo) / (double)(L - 1);
            double t  = (jt == L - 1) ? hi : (lo + (double)jt * st);
            double ts = t / sc;
            double nm = 1.0 / (pow(M_PI, 0.25) * sqrt(sc));
            double g  = nm * exp(-(ts * ts) * 0.5);
            wf = (float)(ri ? (g * sin(5.0 * ts)) : (g * cos(5.0 * ts)));
        }
        _Float16 hv = (_Float16)wf;
        whi[idx] = hv;
        wlo[idx] = (_Float16)(wf - (float)hv);
    }
}

__global__ __launch_bounds__(BT, 6) void wlsc_main(
    const float* __restrict__ x,
    const float* __restrict__ w1, const float* __restrict__ b1,
    const float* __restrict__ w2, const float* __restrict__ b2,
    const float* __restrict__ blend_logit,
    const float* __restrict__ lsc,
    const _Float16* __restrict__ wfh,
    const _Float16* __restrict__ wfl,
    float* __restrict__ out)
{
    __shared__ float cwtb[NS * RS];                          // 16640 B
    __shared__ __align__(16) char ubuf[2 * NCPY * XCS * 2];  // 6400 B
    __shared__ float corr[NS];
    _Float16* xch = (_Float16*)ubuf;
    _Float16* xcl = xch + NCPY * XCS;
    // total LDS = 16640 + 6400 + 64 = 23104 B -> 6 blocks/CU

    const int tid  = threadIdx.x;
    const int tile = blockIdx.x;
    const int bc   = blockIdx.y;
    const int t0   = tile * TW;
    const int c    = bc & (CH - 1);
    const float* xbc = x + (size_t)bc * T_LEN;
    const bool interior = (t0 >= 2) && (t0 + 254 <= T_LEN);   // block-uniform

    if (tid < NS) corr[tid] = expf(lsc[tid]);

    // ---- stage x window as split-f16 into 2 shifted copies ----
    for (int v = tid; v < XWELEM + NCPY; v += BT) {
        int g = t0 - 258 + v;
        if (g < 0)      g = -g;
        if (g >= T_LEN) g = 2 * T_LEN - 2 - g;
        float xv = xbc[g];
        _Float16 hv = (_Float16)xv;
        _Float16 lv = (_Float16)(xv - (float)hv);
        #pragma unroll
        for (int cp = 0; cp < NCPY; ++cp) {
            int idx = v - cp;
            if ((unsigned)idx < XWELEM) {
                xch[cp * XCS + idx] = hv;
                xcl[cp * XCS + idx] = lv;
            }
        }
    }
    __syncthreads();

    // ---- stage 1: CWT via mfma_f32_16x16x32_f16, split-f16 3-product scheme.
    // A layout: A[m=lane&15][k=8*(lane>>4)+j]; Hankel: frag(mt+2,q)=frag(mt,q+1)
    // -> depth-2 queues for m-tile streams mt=4*wid and 4*wid+1 serve all 4. ----
    const int lane = tid & 63;
    const int wid  = tid >> 6;
    const int li   = lane & 15;
    const int hq   = lane >> 4;
    const int abase = (li & 1) * XCS + (li & ~1) + 8 * hq;
    const _Float16* pah = xch + abase;
    const _Float16* pal = xcl + abase;
    const f16x8* wh = reinterpret_cast<const f16x8*>(wfh);
    const f16x8* wl = reinterpret_cast<const f16x8*>(wfl);

#define LOADF(p, off) ({                                                      \
        const _Float16* _q = (p) + (off);                                     \
        f16x2 _a = *(const f16x2*)(_q);                                       \
        f16x2 _b = *(const f16x2*)(_q + 2);                                   \
        f16x2 _c = *(const f16x2*)(_q + 4);                                   \
        f16x2 _d = *(const f16x2*)(_q + 6);                                   \
        f16x8 _r;                                                             \
        _r[0]=_a[0]; _r[1]=_a[1]; _r[2]=_b[0]; _r[3]=_b[1];                   \
        _r[4]=_c[0]; _r[5]=_c[1]; _r[6]=_d[0]; _r[7]=_d[1];                   \
        _r; })
#define MF(A, B, C) __builtin_amdgcn_mfma_f32_16x16x32_f16((A), (B), (C), 0, 0, 0)

    const int s_even = li >> 1;          // scale within group for even-li lanes
    f32x4 ac0, ac1, ac2, ac3;

    // ---- group 1: scales 8-15, chunks 0..16 (table ci = NQ0+q), koff = 0 ----
    {
        #pragma unroll
        for (int i = 0; i < 4; ++i) { ac0[i]=0.f; ac1[i]=0.f; ac2[i]=0.f; ac3[i]=0.f; }
        const int ob = 64 * wid;
        f16x8 G0h = LOADF(pah, ob),      G0l = LOADF(pal, ob);
        f16x8 H0h = LOADF(pah, ob + 16), H0l = LOADF(pal, ob + 16);
        #pragma unroll
        for (int q = 0; q < NQ1; ++q) {
            f16x8 G1h = LOADF(pah, ob + 32 * (q + 1));
            f16x8 G1l = LOADF(pal, ob + 32 * (q + 1));
            f16x8 H1h = LOADF(pah, ob + 16 + 32 * (q + 1));
            f16x8 H1l = LOADF(pal, ob + 16 + 32 * (q + 1));
            f16x8 bh = wh[(NQ0 + q) * 64 + lane];
            f16x8 bl = wl[(NQ0 + q) * 64 + lane];
            ac0 = MF(G0h, bh, ac0); ac0 = MF(G0h, bl, ac0); ac0 = MF(G0l, bh, ac0);
            ac1 = MF(H0h, bh, ac1); ac1 = MF(H0h, bl, ac1); ac1 = MF(H0l, bh, ac1);
            ac2 = MF(G1h, bh, ac2); ac2 = MF(G1h, bl, ac2); ac2 = MF(G1l, bh, ac2);
            ac3 = MF(H1h, bh, ac3); ac3 = MF(H1h, bl, ac3); ac3 = MF(H1l, bh, ac3);
            G0h = G1h; G0l = G1l; H0h = H1h; H0l = H1l;
        }
        // epilogue: C/D row = 4*hq + e, col = li; r/i pair via shfl_xor(1)
        const int s = 8 + s_even;
        #pragma unroll
        for (int mi = 0; mi < 4; ++mi) {
            f32x4 acc = (mi == 0) ? ac0 : (mi == 1) ? ac1 : (mi == 2) ? ac2 : ac3;
            float4 mag;
            #pragma unroll
            for (int e = 0; e < 4; ++e) {
                float cr = acc[e];
                float cim = __shfl_xor(cr, 1);
                float mg = sqrtf(cr * cr + cim * cim);
                if (!interior) {
                    int ta = t0 - 2 + 16 * (4 * wid + mi) + 4 * hq + e;
                    if ((unsigned)ta >= T_LEN) mg = 0.f;
                }
                (&mag.x)[e] = mg;
            }
            if ((lane & 1) == 0)
                *reinterpret_cast<float4*>(cwtb + s * RS + 16 * (4 * wid + mi) + 4 * hq) = mag;
        }
    }

    // ---- group 0: scales 0-7, chunks 0..3 (table ci = q), koff = 192 ----
    {
        #pragma unroll
        for (int i = 0; i < 4; ++i) { ac0[i]=0.f; ac1[i]=0.f; ac2[i]=0.f; ac3[i]=0.f; }
        const int ob = 64 * wid + KOFF0;
        f16x8 G0h = LOADF(pah, ob),      G0l = LOADF(pal, ob);
        f16x8 H0h = LOADF(pah, ob + 16), H0l = LOADF(pal, ob + 16);
        #pragma unroll
        for (int q = 0; q < NQ0; ++q) {
            f16x8 G1h = LOADF(pah, ob + 32 * (q + 1));
            f16x8 G1l = LOADF(pal, ob + 32 * (q + 1));
            f16x8 H1h = LOADF(pah, ob + 16 + 32 * (q + 1));
            f16x8 H1l = LOADF(pal, ob + 16 + 32 * (q + 1));
            f16x8 bh = wh[q * 64 + lane];
            f16x8 bl = wl[q * 64 + lane];
            ac0 = MF(G0h, bh, ac0); ac0 = MF(G0h, bl, ac0); ac0 = MF(G0l, bh, ac0);
            ac1 = MF(H0h, bh, ac1); ac1 = MF(H0h, bl, ac1); ac1 = MF(H0l, bh, ac1);
            ac2 = MF(G1h, bh, ac2); ac2 = MF(G1h, bl, ac2); ac2 = MF(G1l, bh, ac2);
            ac3 = MF(H1h, bh, ac3); ac3 = MF(H1h, bl, ac3); ac3 = MF(H1l, bh, ac3);
            G0h = G1h; G0l = G1l; H0h = H1h; H0l = H1l;
        }
        const int s = s_even;
        #pragma unroll
        for (int mi = 0; mi < 4; ++mi) {
            f32x4 acc = (mi == 0) ? ac0 : (mi == 1) ? ac1 : (mi == 2) ? ac2 : ac3;
            float4 mag;
            #pragma unroll
            for (int e = 0; e < 4; ++e) {
                float cr = acc[e];
                float cim = __shfl_xor(cr, 1);
                float mg = sqrtf(cr * cr + cim * cim);
                if (!interior) {
                    int ta = t0 - 2 + 16 * (4 * wid + mi) + 4 * hq + e;
                    if ((unsigned)ta >= T_LEN) mg = 0.f;
                }
                (&mag.x)[e] = mg;
            }
            if ((lane & 1) == 0)
                *reinterpret_cast<float4*>(cwtb + s * RS + 16 * (4 * wid + mi) + 4 * hq) = mag;
        }
    }
#undef LOADF
#undef MF
    __syncthreads();

    // per-channel weights -> registers
    float W1r[9], W2r[9];
    #pragma unroll
    for (int k = 0; k < 9; ++k) { W1r[k] = w1[c * 9 + k]; W2r[k] = w2[c * 9 + k]; }
    const float B1v = b1[c], B2v = b2[c];
    const float blend = 1.f / (1.f + expf(-blend_logit[0]));

    // ---- stages 2+3 fused: h1 in registers, neighbor columns via shfl. ----
    {
        const int tt1 = 62 * wid + lane;
        const int ta  = t0 - 1 + tt1;
        const bool inb = (unsigned)ta < T_LEN;
        float h1r[NS];
        float rawcv[NS];

        // stage 2: sliding rows, 3 b32 LDS reads per row
        {
            float p0 = 0.f, p1 = 0.f, p2 = 0.f;
            float c0, c1, c2;
            {
                const float* r = cwtb + tt1;
                float cr = corr[0];
                float r2 = r[2];
                rawcv[0] = r2;
                c0 = r[0] * cr; c1 = r[1] * cr; c2 = r2 * cr;
            }
            #pragma unroll
            for (int s = 0; s < NS; ++s) {
                float n0 = 0.f, n1 = 0.f, n2 = 0.f;
                if (s + 1 < NS) {
                    const float* r = cwtb + (s + 1) * RS + tt1;
                    float cr = corr[s + 1];
                    float r2 = r[2];
                    rawcv[s + 1] = r2;
                    n0 = r[0] * cr; n1 = r[1] * cr; n2 = r2 * cr;
                }
                float acc = B1v;
                acc = fmaf(p0, W1r[0], acc); acc = fmaf(p1, W1r[1], acc); acc = fmaf(p2, W1r[2], acc);
                acc = fmaf(c0, W1r[3], acc); acc = fmaf(c1, W1r[4], acc); acc = fmaf(c2, W1r[5], acc);
                acc = fmaf(n0, W1r[6], acc); acc = fmaf(n1, W1r[7], acc); acc = fmaf(n2, W1r[8], acc);
                h1r[s] = inb ? gelu_exact(acc) : 0.f;
                p0 = c0; p1 = c1; p2 = c2;
                c0 = n0; c1 = n1; c2 = n2;
            }
        }

        // stage 3: neighbor columns via shfl_down; division via v_rcp (1 ulp)
        const int t = t0 + tt1;
        float racc = 0.f;
        float pa = 0.f, pb = 0.f, pc = 0.f;
        float ca, cb, cc;
        {
            ca = h1r[0];
            cb = __shfl_down(ca, 1);
            cc = __shfl_down(ca, 2);
        }
        #pragma unroll
        for (int s = 0; s < NS; ++s) {
            float na = 0.f, nb = 0.f, nc = 0.f;
            if (s + 1 < NS) {
                na = h1r[s + 1];
                nb = __shfl_down(na, 1);
                nc = __shfl_down(na, 2);
            }
            float acc = B2v;
            acc = fmaf(pa, W2r[0], acc); acc = fmaf(pb, W2r[1], acc); acc = fmaf(pc, W2r[2], acc);
            acc = fmaf(ca, W2r[3], acc); acc = fmaf(cb, W2r[4], acc); acc = fmaf(cc, W2r[5], acc);
            acc = fmaf(na, W2r[6], acc); acc = fmaf(nb, W2r[7], acc); acc = fmaf(nc, W2r[8], acc);
            float h2v = gelu_exact(acc);
            float cv  = rawcv[s];
            float num = blend * h2v + (1.f - blend) * cv;
            racc = fmaf(num, __builtin_amdgcn_rcpf(cv + 1e-8f), racc);
            pa = ca; pb = cb; pc = cc;
            ca = na; cb = nb; cc = nc;
        }
        if (lane < 62 && t < T_LEN)
            out[(size_t)bc * T_LEN + t] = xbc[t] * racc * (1.f / 16.f);
    }
}

extern "C" void kernel_launch(void* const* d_in, const int* in_sizes, int n_in,
                              void* d_out, int out_size, void* d_ws, size_t ws_size,
                              hipStream_t stream) {
    const float* x  = (const float*)d_in[0];
    const float* w1 = (const float*)d_in[1];
    const float* b1 = (const float*)d_in[2];
    const float* w2 = (const float*)d_in[3];
    const float* b2 = (const float*)d_in[4];
    const float* bl = (const float*)d_in[5];
    const float* ls = (const float*)d_in[6];
    float* out = (float*)d_out;

    _Float16* whi = (_Float16*)d_ws;          // NFRAG f16
    _Float16* wlo = whi + NFRAG;              // NFRAG f16

    hipLaunchKernelGGL(wavelet_init, dim3(42), dim3(256), 0, stream, whi, wlo);

    dim3 grid(NTILES, BATCH * CH);
    hipLaunchKernelGGL(wlsc_main, grid, dim3(BT), 0, stream,
                       x, w1, b1, w2, b2, bl, ls, whi, wlo, out);
}